// Round 8
// baseline (718.814 us; speedup 1.0000x reference)
//
#include <hip/hip_runtime.h>
#include <cmath>
#include <cstdint>

typedef float floatx4 __attribute__((ext_vector_type(4)));

#define EPS_ 1e-5f
#define QSCALE 0.17677669529663689f

// ---------- async global->LDS (16B per lane) ----------
__device__ __forceinline__ void gload16(const uint8_t* g, uint8_t* l) {
  __builtin_amdgcn_global_load_lds(
      (const __attribute__((address_space(1))) void*)g,
      (__attribute__((address_space(3))) void*)l, 16, 0, 0);
}

// ---------- fp8 e4m3 pack (word-select must be an immediate) ----------
template<bool HI>
__device__ __forceinline__ int pk_fp8(float a, float b, int old) {
  return __builtin_amdgcn_cvt_pk_fp8_f32(a, b, old, HI);
}
__device__ __forceinline__ int pk_fp8x4(float v0, float v1, float v2, float v3) {
  int w = pk_fp8<false>(v0, v1, 0);
  return pk_fp8<true>(v2, v3, w);
}

// ---------- bf16 helpers (RNE) ----------
__device__ __forceinline__ uint16_t f2bf(float f) {
  uint32_t u = __float_as_uint(f);
  return (uint16_t)((u + 0x7fffu + ((u >> 16) & 1u)) >> 16);
}
__device__ __forceinline__ float bf2f(uint16_t h) {
  return __uint_as_float(((uint32_t)h) << 16);
}

// Fragment-major layout for all GEMM operands:
//   addr(m, k) = (m & ~15)*K + (k>>3)*128 + (m & 15)*8 + (k & 7)

// ---------- fp32 weights -> fp8 frag-major (col-permuted: panel 4g+j slot lm = col 64g+4lm+j) ----------
template<int K>
__global__ void cvt_frag(const float* __restrict__ s, uint8_t* __restrict__ d, int n4) {
  const int i = blockIdx.x * 256 + threadIdx.x;
  if (i >= n4) return;
  const int kq = K >> 2;
  const int n = i / kq;
  const int k = (i - n * kq) << 2;
  const float4 v = ((const float4*)s)[i];
  const int panel = ((n >> 6) << 2) + (n & 3);
  const int lm = (n >> 2) & 15;
  const long addr = (long)panel * (16 * K) + ((k >> 3) << 7) + (lm << 3) + (k & 4);
  *(int*)(d + addr) = pk_fp8x4(v.x, v.y, v.z, v.w);
}

// ---------- LN1 stats over C for NCHW input ----------
__global__ __launch_bounds__(256)
void ln_stats_nchw(const float* __restrict__ x, float* __restrict__ mu, float* __restrict__ rs) {
  const int tl = threadIdx.x & 63;
  const int wv = threadIdx.x >> 6;
  const int t = blockIdx.x * 64 + tl;       // token = b*196 + p
  const int b = t / 196;
  const int p = t - b * 196;
  const float* xp = x + (long)b * 100352 + p;
  float s = 0.f, ss = 0.f;
  const int cbeg = wv * 128;
  for (int c = cbeg; c < cbeg + 128; ++c) {
    const float v = xp[(long)c * 196];
    s += v; ss += v * v;
  }
  __shared__ float sb[4][64], qb[4][64];
  sb[wv][tl] = s; qb[wv][tl] = ss;
  __syncthreads();
  if (wv == 0) {
    s  = sb[0][tl] + sb[1][tl] + sb[2][tl] + sb[3][tl];
    ss = qb[0][tl] + qb[1][tl] + qb[2][tl] + qb[3][tl];
    const float m = s * (1.f / 512.f);
    const float var = ss * (1.f / 512.f) - m * m;
    mu[t] = m;
    rs[t] = rsqrtf(var + EPS_);
  }
}

// ---------- LN1 apply: NCHW -> frag-major fp8 tokens ----------
__global__ __launch_bounds__(256)
void ln1_apply(const float* __restrict__ x, const float* __restrict__ mu, const float* __restrict__ rs,
               const float* __restrict__ w, const float* __restrict__ bb, uint8_t* __restrict__ A) {
  __shared__ float tile[64][53];
  const int bid = blockIdx.x;
  const int ct = bid & 7;
  const int pt = (bid >> 3) & 3;
  const int b = bid >> 5;
  const int p0 = pt * 49, c0 = ct * 64;
  const long xbase = (long)b * 100352;
  for (int idx = threadIdx.x; idx < 3136; idx += 256) {
    const int cl = idx / 49;
    const int pl = idx - cl * 49;
    tile[cl][pl] = x[xbase + (long)(c0 + cl) * 196 + p0 + pl];
  }
  __syncthreads();
  const int tbase = b * 196 + p0;
  for (int idx = threadIdx.x; idx < 784; idx += 256) {
    const int pl = idx >> 4;                // 0..48
    const int cq = (idx & 15) << 2;         // 0..60 step 4
    const int t = tbase + pl;
    const int c = c0 + cq;
    const float m = mu[t], rr = rs[t];
    const float v0 = (tile[cq + 0][pl] - m) * rr * w[c + 0] + bb[c + 0];
    const float v1 = (tile[cq + 1][pl] - m) * rr * w[c + 1] + bb[c + 1];
    const float v2 = (tile[cq + 2][pl] - m) * rr * w[c + 2] + bb[c + 2];
    const float v3 = (tile[cq + 3][pl] - m) * rr * w[c + 3] + bb[c + 3];
    const long addr = (long)(t & ~15) * 512 + ((c >> 3) << 7) + ((t & 15) << 3) + (c & 4);
    *(int*)(A + addr) = pk_fp8x4(v0, v1, v2, v3);
  }
}

// ---------- LN2: one block per 16-token panel; X1 bf16 -> frag-major fp8 ----------
__global__ __launch_bounds__(256)
void ln2_panel(const uint16_t* __restrict__ Xb, const float* __restrict__ S1,
               const float* __restrict__ S2, const float* __restrict__ w,
               const float* __restrict__ bb, uint8_t* __restrict__ Z) {
  __shared__ float xs[16 * 516];
  const int p = blockIdx.x;
  const int t0 = p * 16;
  for (int idx = threadIdx.x; idx < 1024; idx += 256) {
    const int tl = idx >> 6;                 // token 0..15
    const int c8 = (idx & 63) << 3;          // 0..504 step 8
    const uint4 raw = *(const uint4*)(Xb + ((long)(t0 + tl) << 9) + c8);
    float* xr = xs + tl * 516 + c8;
    xr[0] = bf2f((uint16_t)(raw.x & 0xffff)); xr[1] = bf2f((uint16_t)(raw.x >> 16));
    xr[2] = bf2f((uint16_t)(raw.y & 0xffff)); xr[3] = bf2f((uint16_t)(raw.y >> 16));
    xr[4] = bf2f((uint16_t)(raw.z & 0xffff)); xr[5] = bf2f((uint16_t)(raw.z >> 16));
    xr[6] = bf2f((uint16_t)(raw.w & 0xffff)); xr[7] = bf2f((uint16_t)(raw.w >> 16));
  }
  __syncthreads();
  uint8_t* zp = Z + (long)p * 8192;
  for (int e = threadIdx.x; e < 2048; e += 256) {
    const int off = e << 2;            // byte offset in panel
    const int k8 = off >> 7;
    const int tl = (off >> 3) & 15;
    const int c = (k8 << 3) + (off & 4);
    const int t = t0 + tl;
    const float m = S1[t] * (1.f / 512.f);
    const float var = S2[t] * (1.f / 512.f) - m * m;
    const float r = rsqrtf(var + EPS_);
    const float* xr = xs + tl * 516 + c;
    const float v0 = (xr[0] - m) * r * w[c + 0] + bb[c + 0];
    const float v1 = (xr[1] - m) * r * w[c + 1] + bb[c + 1];
    const float v2 = (xr[2] - m) * r * w[c + 2] + bb[c + 2];
    const float v3 = (xr[3] - m) * r * w[c + 3] + bb[c + 3];
    *(int*)(zp + off) = pk_fp8x4(v0, v1, v2, v3);
  }
}

// ---------- fp8 MFMA GEMM: B LDS-resident (64 cols), A direct-global frag-major, barrier-free K-loop ----------
// Block = 4 waves x (MI*16 rows) x 64 cols.
// EPI 0: qkv  -> fp8 token-major (N stride), q-scale for col<512
// EPI 1: proj -> bf16 X1 = x(NCHW) + g1*(acc+b), token-major; fused LN2 raw-sum atomics
// EPI 2: fc1  -> fp8 frag-major (K2=2048) with exact GELU
// EPI 3: fc2  -> f32 NCHW via LDS tile exchange (two 128-row halves); res = X1 bf16
template<int MI, int K, int EPI>
__global__ __launch_bounds__(256, 1)
void gemm_bl(const uint8_t* __restrict__ A, const uint8_t* __restrict__ Bw,
             const float* __restrict__ bias, const float* __restrict__ res,
             const uint16_t* __restrict__ resb, const float* __restrict__ gamma,
             uint8_t* __restrict__ outb, float* __restrict__ outf,
             uint16_t* __restrict__ outh, float* __restrict__ S1, float* __restrict__ S2,
             const int N) {
  __shared__ uint8_t Bs[33280];     // 32 KB B chunk; EPI3 reuses as 64x130 f32 tile
  const int tid = threadIdx.x;
  const int wave = tid >> 6, lane = tid & 63;
  const int lm = lane & 15, lq = lane >> 4;
  const long m0 = (long)blockIdx.x * (MI * 64);
  const int g = blockIdx.y;                 // 64-col group
  const long n0 = (long)g << 6;
  const uint8_t* abase = A + (m0 + wave * MI * 16) * (long)K + (lane << 3);
  floatx4 acc[MI][4] = {};
  constexpr int NKS = K / 32;
  long aC[MI], aN[MI];
  #pragma unroll
  for (int i = 0; i < MI; ++i) aC[i] = *(const long*)(abase + (long)i * 16 * K);
  #pragma unroll
  for (int ph = 0; ph < K / 512; ++ph) {
    const uint8_t* bsrc = Bw + n0 * K + ph * 8192;
    #pragma unroll
    for (int j = 0; j < 4; ++j)
      #pragma unroll
      for (int c = 0; c < 2; ++c)
        gload16(bsrc + (long)j * 16 * K + c * 4096 + tid * 16,
                Bs + j * 8192 + c * 4096 + tid * 16);
    __syncthreads();
    #pragma unroll
    for (int ksl = 0; ksl < 16; ++ksl) {
      const int sg = ph * 16 + ksl;
      if (sg + 1 < NKS) {
        #pragma unroll
        for (int i = 0; i < MI; ++i)
          aN[i] = *(const long*)(abase + (long)i * 16 * K + (sg + 1) * 512);
      }
      long bf[4];
      #pragma unroll
      for (int j = 0; j < 4; ++j)
        bf[j] = *(const long*)(Bs + j * 8192 + ksl * 512 + (lane << 3));
      #pragma unroll
      for (int i = 0; i < MI; ++i)
        #pragma unroll
        for (int j = 0; j < 4; ++j)
          acc[i][j] = __builtin_amdgcn_mfma_f32_16x16x32_fp8_fp8(aC[i], bf[j], acc[i][j], 0, 0, 0);
      #pragma unroll
      for (int i = 0; i < MI; ++i) aC[i] = aN[i];
    }
    if (K / 512 > 1 && ph + 1 < K / 512) __syncthreads();
  }
  const int cb = (g << 6) + (lm << 2);
  const float4 b4 = *(const float4*)(bias + cb);
  float4 g4 = make_float4(0.f, 0.f, 0.f, 0.f);
  if (EPI == 1 || EPI == 3) g4 = *(const float4*)(gamma + cb);
  const float qs = (EPI == 0 && cb < 512) ? QSCALE : 1.f;
  if (EPI != 3) {
    #pragma unroll
    for (int i = 0; i < MI; ++i) {
      #pragma unroll
      for (int r = 0; r < 4; ++r) {
        const long rowg = m0 + wave * MI * 16 + i * 16 + lq * 4 + r;
        float v0 = acc[i][0][r] + b4.x;
        float v1 = acc[i][1][r] + b4.y;
        float v2 = acc[i][2][r] + b4.z;
        float v3 = acc[i][3][r] + b4.w;
        if (EPI == 0) {
          *(int*)(outb + rowg * (long)N + cb) = pk_fp8x4(v0 * qs, v1 * qs, v2 * qs, v3 * qs);
        } else if (EPI == 2) {
          v0 = 0.5f * v0 * (1.f + erff(v0 * 0.70710678118654752f));
          v1 = 0.5f * v1 * (1.f + erff(v1 * 0.70710678118654752f));
          v2 = 0.5f * v2 * (1.f + erff(v2 * 0.70710678118654752f));
          v3 = 0.5f * v3 * (1.f + erff(v3 * 0.70710678118654752f));
          const long addr = (rowg & ~15L) * 2048 + ((cb >> 3) << 7) + ((rowg & 15) << 3) + (cb & 4);
          *(int*)(outb + addr) = pk_fp8x4(v0, v1, v2, v3);
        } else {   // EPI 1
          const unsigned rg = (unsigned)rowg;
          const unsigned bi = rg / 196u;
          const unsigned p = rg - bi * 196u;
          const float* xr = res + (long)bi * 100352 + p;
          const float o0 = xr[(long)(cb + 0) * 196] + g4.x * v0;
          const float o1 = xr[(long)(cb + 1) * 196] + g4.y * v1;
          const float o2 = xr[(long)(cb + 2) * 196] + g4.z * v2;
          const float o3 = xr[(long)(cb + 3) * 196] + g4.w * v3;
          ushort4 hv;
          hv.x = f2bf(o0); hv.y = f2bf(o1); hv.z = f2bf(o2); hv.w = f2bf(o3);
          *(ushort4*)(outh + rowg * 512 + cb) = hv;
          const float q0 = bf2f(hv.x), q1 = bf2f(hv.y), q2 = bf2f(hv.z), q3 = bf2f(hv.w);
          float s = q0 + q1 + q2 + q3;
          float ss = q0 * q0 + q1 * q1 + q2 * q2 + q3 * q3;
          s += __shfl_xor(s, 1);  ss += __shfl_xor(ss, 1);
          s += __shfl_xor(s, 2);  ss += __shfl_xor(ss, 2);
          s += __shfl_xor(s, 4);  ss += __shfl_xor(ss, 4);
          s += __shfl_xor(s, 8);  ss += __shfl_xor(ss, 8);
          if (lm == 0) {
            atomicAdd(S1 + rowg, s);
            atomicAdd(S2 + rowg, ss);
          }
        }
      }
    }
  } else {
    // EPI 3: NCHW via LDS exchange, two 128-row halves (rows m0+half*128 .. +127)
    float* T = (float*)Bs;
    __syncthreads();
    #pragma unroll
    for (int half = 0; half < 2; ++half) {
      if ((wave >> 1) == half) {
        #pragma unroll
        for (int i = 0; i < MI; ++i) {
          #pragma unroll
          for (int r = 0; r < 4; ++r) {
            const long rowg = m0 + wave * MI * 16 + i * 16 + lq * 4 + r;
            const int rl = (int)(rowg - m0) - half * 128;
            const ushort4 rb = *(const ushort4*)(resb + rowg * 512 + cb);
            T[(lm * 4 + 0) * 130 + rl] = bf2f(rb.x) + g4.x * (acc[i][0][r] + b4.x);
            T[(lm * 4 + 1) * 130 + rl] = bf2f(rb.y) + g4.y * (acc[i][1][r] + b4.y);
            T[(lm * 4 + 2) * 130 + rl] = bf2f(rb.z) + g4.z * (acc[i][2][r] + b4.z);
            T[(lm * 4 + 3) * 130 + rl] = bf2f(rb.w) + g4.w * (acc[i][3][r] + b4.w);
          }
        }
      }
      __syncthreads();
      #pragma unroll
      for (int t2 = 0; t2 < 32; ++t2) {
        const int idx = t2 * 256 + tid;
        const int rl = idx & 127;
        const int ch = idx >> 7;
        const unsigned m = (unsigned)(m0 + half * 128 + rl);
        const unsigned bi = m / 196u;
        const unsigned p = m - bi * 196u;
        outf[(long)bi * 100352 + (long)(n0 + ch) * 196 + p] = T[ch * 130 + rl];
      }
      __syncthreads();
    }
  }
}

// ---------- BM table: bias+mask+padding in MFMA C-layout order ----------
__global__ __launch_bounds__(256)
void bm_build(const float* __restrict__ rel_bias, float* __restrict__ BM) {
  const int hw = blockIdx.x;           // head*4 + wpos
  const int head = hw >> 2, wpos = hw & 3;
  const int wi = wpos >> 1, wj = wpos & 1;
  for (int k = 0; k < 4; ++k) {
    const int idx = k * 256 + threadIdx.x;   // tile*64 + lane
    const int tile = idx >> 6, l = idx & 63;
    const int qi = tile >> 2, ti = tile & 3;
    const int n = l & 15, g = l >> 4;
    const int query = qi * 16 + n;
    const int qy = query / 7, qx = query - qy * 7;
    const int hh = wi * 7 + qy, ww = wj * 7 + qx;
    const int ri = (hh < 7 ? 0 : (hh < 11 ? 1 : 2)) * 3 + (ww < 7 ? 0 : (ww < 11 ? 1 : 2));
    float4 ov;
    float vv[4];
    #pragma unroll
    for (int r = 0; r < 4; ++r) {
      const int key = ti * 16 + g * 4 + r;
      float v;
      if (query >= 49 || key >= 49) {
        v = -3.0e38f;
      } else {
        const int ky = key / 7, kx = key - ky * 7;
        const int bidx = (qy - ky + 6) * 13 + (qx - kx + 6);
        const int h2 = wi * 7 + ky, w2 = wj * 7 + kx;
        const int rj = (h2 < 7 ? 0 : (h2 < 11 ? 1 : 2)) * 3 + (w2 < 7 ? 0 : (w2 < 11 ? 1 : 2));
        v = rel_bias[bidx * 16 + head] + ((ri != rj) ? -100.f : 0.f);
      }
      vv[r] = v;
    }
    ov.x = vv[0]; ov.y = vv[1]; ov.z = vv[2]; ov.w = vv[3];
    *(float4*)(BM + ((long)(hw * 16 + tile) << 8) + l * 4) = ov;
  }
}

// ---------- 4x4 byte transpose ----------
__device__ __forceinline__ void tr4(const uint32_t d[4], uint32_t o[4]) {
  #pragma unroll
  for (int c = 0; c < 4; ++c)
    o[c] = ((d[0] >> (8 * c)) & 0xffu) | (((d[1] >> (8 * c)) & 0xffu) << 8)
         | (((d[2] >> (8 * c)) & 0xffu) << 16) | (((d[3] >> (8 * c)) & 0xffu) << 24);
}

// ---------- MFMA windowed attention: one wave per (window, head); AT written frag-major ----------
__global__ __launch_bounds__(256)
void attn_mfma(const uint8_t* __restrict__ QKV, const float* __restrict__ BM,
               uint8_t* __restrict__ AT) {
  __shared__ uint8_t lds[4][9984];   // per-wave: Pb 64x72, Vt 32x72, Ot 64x48
  const int wave = threadIdx.x >> 6, lane = threadIdx.x & 63;
  const int n = lane & 15, g = lane >> 4;
  const int gw = blockIdx.x * 4 + wave;
  const int wd = gw >> 4, head = gw & 15;
  const int b = wd >> 2, wpos = wd & 3;
  const int wi = wpos >> 1, wj = wpos & 1;
  uint8_t* Pb = lds[wave];
  uint8_t* Vt = lds[wave] + 4608;
  uint8_t* Ot = lds[wave] + 6912;
  const long base = (long)b * 196 * 1536;
  auto tok = [&](int slot) -> int {
    const int ty = slot / 7, tx = slot - ty * 7;
    int h = wi * 7 + ty + 3; if (h >= 14) h -= 14;
    int w = wj * 7 + tx + 3; if (w >= 14) w -= 14;
    return h * 14 + w;
  };
  long Ak[4], Bq[4];
  #pragma unroll
  for (int t4 = 0; t4 < 4; ++t4) {
    int slot = t4 * 16 + n; if (slot > 48) slot = 48;
    const long tb = base + (long)tok(slot) * 1536 + head * 32 + g * 8;
    Bq[t4] = *(const long*)(QKV + tb);          // Q rows (B operand)
    Ak[t4] = *(const long*)(QKV + tb + 512);    // K rows (A operand)
  }
  #pragma unroll
  for (int bb2 = 0; bb2 < 2; ++bb2) {
    const int blk = lane + bb2 * 64;
    const int dq = blk >> 4, tq = blk & 15;
    uint32_t d4[4], o4[4];
    #pragma unroll
    for (int r = 0; r < 4; ++r) {
      int slot = tq * 4 + r; if (slot > 48) slot = 48;
      d4[r] = *(const uint32_t*)(QKV + base + (long)tok(slot) * 1536 + 1024 + head * 32 + dq * 4);
    }
    tr4(d4, o4);
    #pragma unroll
    for (int c = 0; c < 4; ++c)
      *(uint32_t*)(Vt + (dq * 4 + c) * 72 + tq * 4) = o4[c];
  }
  floatx4 acc[4][4];
  const float* bmw = BM + ((long)(head * 4 + wpos) << 12) + lane * 4;
  #pragma unroll
  for (int qi = 0; qi < 4; ++qi)
    #pragma unroll
    for (int ti = 0; ti < 4; ++ti) {
      const float4 bv = *(const float4*)(bmw + ((qi * 4 + ti) << 8));
      acc[qi][ti][0] = bv.x; acc[qi][ti][1] = bv.y;
      acc[qi][ti][2] = bv.z; acc[qi][ti][3] = bv.w;
    }
  #pragma unroll
  for (int qi = 0; qi < 4; ++qi)
    #pragma unroll
    for (int ti = 0; ti < 4; ++ti)
      acc[qi][ti] = __builtin_amdgcn_mfma_f32_16x16x32_fp8_fp8(Ak[ti], Bq[qi], acc[qi][ti], 0, 0, 0);
  #pragma unroll
  for (int qi = 0; qi < 4; ++qi) {
    float mx = -3.0e38f;
    #pragma unroll
    for (int ti = 0; ti < 4; ++ti)
      #pragma unroll
      for (int r = 0; r < 4; ++r) mx = fmaxf(mx, acc[qi][ti][r]);
    mx = fmaxf(mx, __shfl_xor(mx, 16));
    mx = fmaxf(mx, __shfl_xor(mx, 32));
    float sum = 0.f;
    #pragma unroll
    for (int ti = 0; ti < 4; ++ti)
      #pragma unroll
      for (int r = 0; r < 4; ++r) {
        const float e = __expf(acc[qi][ti][r] - mx);
        acc[qi][ti][r] = e; sum += e;
      }
    sum += __shfl_xor(sum, 16);
    sum += __shfl_xor(sum, 32);
    const float inv = 1.f / sum;
    #pragma unroll
    for (int ti = 0; ti < 4; ++ti) {
      const int pw = pk_fp8x4(acc[qi][ti][0] * inv, acc[qi][ti][1] * inv,
                              acc[qi][ti][2] * inv, acc[qi][ti][3] * inv);
      *(uint32_t*)(Pb + (qi * 16 + n) * 72 + ti * 16 + g * 4) = pw;
    }
  }
  asm volatile("s_waitcnt lgkmcnt(0)" ::: "memory");
  long Bv[2][2];
  #pragma unroll
  for (int ni = 0; ni < 2; ++ni)
    #pragma unroll
    for (int s = 0; s < 2; ++s)
      Bv[ni][s] = *(const long*)(Vt + (ni * 16 + n) * 72 + s * 32 + g * 8);
  floatx4 o[4][2] = {};
  #pragma unroll
  for (int qi = 0; qi < 4; ++qi)
    #pragma unroll
    for (int s = 0; s < 2; ++s) {
      const long Ap = *(const long*)(Pb + (qi * 16 + n) * 72 + s * 32 + g * 8);
      #pragma unroll
      for (int ni = 0; ni < 2; ++ni)
        o[qi][ni] = __builtin_amdgcn_mfma_f32_16x16x32_fp8_fp8(Ap, Bv[ni][s], o[qi][ni], 0, 0, 0);
    }
  #pragma unroll
  for (int qi = 0; qi < 4; ++qi)
    #pragma unroll
    for (int ni = 0; ni < 2; ++ni)
      #pragma unroll
      for (int r = 0; r < 4; ++r)
        Ot[(qi * 16 + g * 4 + r) * 48 + ni * 16 + n] =
            (uint8_t)(pk_fp8<false>(o[qi][ni][r], 0.f, 0) & 0xff);
  asm volatile("s_waitcnt lgkmcnt(0)" ::: "memory");
  if (lane < 49) {
    const int m = b * 196 + tok(lane);
    uint8_t* opb = AT + (long)(m & ~15) * 512 + ((m & 15) << 3);
    #pragma unroll
    for (int d8 = 0; d8 < 4; ++d8)
      *(long*)(opb + (head * 4 + d8) * 128) = *(const long*)(Ot + lane * 48 + d8 * 8);
  }
}

extern "C" void kernel_launch(void* const* d_in, const int* in_sizes, int n_in,
                              void* d_out, int out_size, void* d_ws, size_t ws_size,
                              hipStream_t stream) {
  const float* x      = (const float*)d_in[0];
  const float* ln1_w  = (const float*)d_in[1];
  const float* ln1_b  = (const float*)d_in[2];
  const float* qkv_w  = (const float*)d_in[3];
  const float* qkv_b  = (const float*)d_in[4];
  const float* relb   = (const float*)d_in[5];
  const float* proj_w = (const float*)d_in[6];
  const float* proj_b = (const float*)d_in[7];
  const float* gamma1 = (const float*)d_in[8];
  const float* ln2_w  = (const float*)d_in[9];
  const float* ln2_b  = (const float*)d_in[10];
  const float* fc1_w  = (const float*)d_in[11];
  const float* fc1_b  = (const float*)d_in[12];
  const float* fc2_w  = (const float*)d_in[13];
  const float* fc2_b  = (const float*)d_in[14];
  const float* gamma2 = (const float*)d_in[15];
  float* out = (float*)d_out;
  char* ws = (char*)d_ws;

  float*    mu1 = (float*)(ws + 0);
  float*    rs1 = (float*)(ws + 100352);
  float*    S1  = (float*)(ws + 200704);      // LN2 raw sum
  float*    S2  = (float*)(ws + 301056);      // LN2 raw sumsq
  uint8_t*  Wq  = (uint8_t*)(ws + 401408);    //   786,432 B frag-major
  uint8_t*  Wp  = (uint8_t*)(ws + 1187840);   //   262,144 B
  uint8_t*  W1  = (uint8_t*)(ws + 1449984);   // 1,048,576 B
  uint8_t*  W2  = (uint8_t*)(ws + 2498560);   // 1,048,576 B
  float*    BMt = (float*)  (ws + 3547136);   // 1,048,576 B bias+mask table
  uint8_t*  Afp = (uint8_t*)(ws + 4595712);   // 12,845,056 B frag-major tokens (LN1, later LN2)
  uint16_t* X1b = (uint16_t*)(ws + 68820992); // 25,690,112 B token-major bf16
  uint8_t*  QKV = (uint8_t*)(ws + 120201216); // 38,535,168 B token-major fp8
  uint8_t*  AT  = (uint8_t*)(ws + 158736384); // 12,845,056 B frag-major fp8
  uint8_t*  Hb  = (uint8_t*)(ws + 120201216); // 51,380,224 B frag-major, overlaps dead QKV+AT

  // zero LN2 sum buffers (atomics accumulate during proj epilogue)
  hipMemsetAsync(ws + 200704, 0, 200704, stream);

  // weights -> fp8 frag-major, BM table
  cvt_frag<512> <<<768,  256, 0, stream>>>(qkv_w, Wq, 196608);
  cvt_frag<512> <<<256,  256, 0, stream>>>(proj_w, Wp, 65536);
  cvt_frag<512> <<<1024, 256, 0, stream>>>(fc1_w, W1, 262144);
  cvt_frag<2048><<<1024, 256, 0, stream>>>(fc2_w, W2, 262144);
  bm_build<<<64, 256, 0, stream>>>(relb, BMt);

  // LN1 -> frag-major fp8 tokens
  ln_stats_nchw<<<392, 256, 0, stream>>>(x, mu1, rs1);
  ln1_apply<<<4096, 256, 0, stream>>>(x, mu1, rs1, ln1_w, ln1_b, Afp);

  // qkv GEMM (q pre-scaled), token-major QKV out
  gemm_bl<8, 512, 0><<<dim3(49, 24), 256, 0, stream>>>(Afp, Wq, qkv_b, nullptr, nullptr, nullptr, QKV, nullptr, nullptr, nullptr, nullptr, 1536);

  // shifted-window attention (MFMA), frag-major AT out
  attn_mfma<<<2048, 256, 0, stream>>>(QKV, BMt, AT);

  // proj GEMM: X1b(bf16) = x(NCHW) + g1*(out+b); fused LN2 stats
  gemm_bl<4, 512, 1><<<dim3(98, 8), 256, 0, stream>>>(AT, Wp, proj_b, x, nullptr, gamma1, nullptr, nullptr, X1b, S1, S2, 512);

  // LN2 apply -> frag-major fp8 tokens
  ln2_panel<<<1568, 256, 0, stream>>>(X1b, S1, S2, ln2_w, ln2_b, Afp);

  // MLP: fc1 -> frag-major Hb (gelu); fc2 -> NCHW out via LDS exchange
  gemm_bl<8, 512, 2><<<dim3(49, 32), 256, 0, stream>>>(Afp, W1, fc1_b, nullptr, nullptr, nullptr, Hb, nullptr, nullptr, nullptr, nullptr, 2048);
  gemm_bl<4, 2048, 3><<<dim3(98, 8), 256, 0, stream>>>(Hb, W2, fc2_b, nullptr, X1b, gamma2, nullptr, out, nullptr, nullptr, nullptr, 512);
}

// Round 9
// 430.794 us; speedup vs baseline: 1.6686x; 1.6686x over previous
//
#include <hip/hip_runtime.h>
#include <cmath>
#include <cstdint>

typedef float floatx4 __attribute__((ext_vector_type(4)));

#define EPS_ 1e-5f
#define QSCALE 0.17677669529663689f

// ---------- async global->LDS (16B per lane) ----------
__device__ __forceinline__ void gload16(const uint8_t* g, uint8_t* l) {
  __builtin_amdgcn_global_load_lds(
      (const __attribute__((address_space(1))) void*)g,
      (__attribute__((address_space(3))) void*)l, 16, 0, 0);
}

// ---------- fp8 e4m3 pack (word-select must be an immediate) ----------
template<bool HI>
__device__ __forceinline__ int pk_fp8(float a, float b, int old) {
  return __builtin_amdgcn_cvt_pk_fp8_f32(a, b, old, HI);
}
__device__ __forceinline__ int pk_fp8x4(float v0, float v1, float v2, float v3) {
  int w = pk_fp8<false>(v0, v1, 0);
  return pk_fp8<true>(v2, v3, w);
}

// ---------- bf16 helpers (RNE) ----------
__device__ __forceinline__ uint16_t f2bf(float f) {
  uint32_t u = __float_as_uint(f);
  return (uint16_t)((u + 0x7fffu + ((u >> 16) & 1u)) >> 16);
}
__device__ __forceinline__ float bf2f(uint16_t h) {
  return __uint_as_float(((uint32_t)h) << 16);
}

// Fragment-major layout for all GEMM operands:
//   addr(m, k) = (m & ~15)*K + (k>>3)*128 + (m & 15)*8 + (k & 7)

// ---------- fp32 weights -> fp8 frag-major (col-permuted: panel 4g+j slot lm = col 64g+4lm+j) ----------
template<int K>
__global__ void cvt_frag(const float* __restrict__ s, uint8_t* __restrict__ d, int n4) {
  const int i = blockIdx.x * 256 + threadIdx.x;
  if (i >= n4) return;
  const int kq = K >> 2;
  const int n = i / kq;
  const int k = (i - n * kq) << 2;
  const float4 v = ((const float4*)s)[i];
  const int panel = ((n >> 6) << 2) + (n & 3);
  const int lm = (n >> 2) & 15;
  const long addr = (long)panel * (16 * K) + ((k >> 3) << 7) + (lm << 3) + (k & 4);
  *(int*)(d + addr) = pk_fp8x4(v.x, v.y, v.z, v.w);
}

// ---------- LN1 stats over C for NCHW input ----------
__global__ __launch_bounds__(256)
void ln_stats_nchw(const float* __restrict__ x, float* __restrict__ mu, float* __restrict__ rs) {
  const int tl = threadIdx.x & 63;
  const int wv = threadIdx.x >> 6;
  const int t = blockIdx.x * 64 + tl;       // token = b*196 + p
  const int b = t / 196;
  const int p = t - b * 196;
  const float* xp = x + (long)b * 100352 + p;
  float s = 0.f, ss = 0.f;
  const int cbeg = wv * 128;
  for (int c = cbeg; c < cbeg + 128; ++c) {
    const float v = xp[(long)c * 196];
    s += v; ss += v * v;
  }
  __shared__ float sb[4][64], qb[4][64];
  sb[wv][tl] = s; qb[wv][tl] = ss;
  __syncthreads();
  if (wv == 0) {
    s  = sb[0][tl] + sb[1][tl] + sb[2][tl] + sb[3][tl];
    ss = qb[0][tl] + qb[1][tl] + qb[2][tl] + qb[3][tl];
    const float m = s * (1.f / 512.f);
    const float var = ss * (1.f / 512.f) - m * m;
    mu[t] = m;
    rs[t] = rsqrtf(var + EPS_);
  }
}

// ---------- LN1 apply: NCHW -> frag-major fp8 tokens ----------
__global__ __launch_bounds__(256)
void ln1_apply(const float* __restrict__ x, const float* __restrict__ mu, const float* __restrict__ rs,
               const float* __restrict__ w, const float* __restrict__ bb, uint8_t* __restrict__ A) {
  __shared__ float tile[64][53];
  const int bid = blockIdx.x;
  const int ct = bid & 7;
  const int pt = (bid >> 3) & 3;
  const int b = bid >> 5;
  const int p0 = pt * 49, c0 = ct * 64;
  const long xbase = (long)b * 100352;
  for (int idx = threadIdx.x; idx < 3136; idx += 256) {
    const int cl = idx / 49;
    const int pl = idx - cl * 49;
    tile[cl][pl] = x[xbase + (long)(c0 + cl) * 196 + p0 + pl];
  }
  __syncthreads();
  const int tbase = b * 196 + p0;
  for (int idx = threadIdx.x; idx < 784; idx += 256) {
    const int pl = idx >> 4;                // 0..48
    const int cq = (idx & 15) << 2;         // 0..60 step 4
    const int t = tbase + pl;
    const int c = c0 + cq;
    const float m = mu[t], rr = rs[t];
    const float v0 = (tile[cq + 0][pl] - m) * rr * w[c + 0] + bb[c + 0];
    const float v1 = (tile[cq + 1][pl] - m) * rr * w[c + 1] + bb[c + 1];
    const float v2 = (tile[cq + 2][pl] - m) * rr * w[c + 2] + bb[c + 2];
    const float v3 = (tile[cq + 3][pl] - m) * rr * w[c + 3] + bb[c + 3];
    const long addr = (long)(t & ~15) * 512 + ((c >> 3) << 7) + ((t & 15) << 3) + (c & 4);
    *(int*)(A + addr) = pk_fp8x4(v0, v1, v2, v3);
  }
}

// ---------- LN2: one block per 16-token panel; X1 bf16 -> frag-major fp8 ----------
__global__ __launch_bounds__(256)
void ln2_panel(const uint16_t* __restrict__ Xb, const float* __restrict__ S1,
               const float* __restrict__ S2, const float* __restrict__ w,
               const float* __restrict__ bb, uint8_t* __restrict__ Z) {
  __shared__ float xs[16 * 516];
  const int p = blockIdx.x;
  const int t0 = p * 16;
  for (int idx = threadIdx.x; idx < 1024; idx += 256) {
    const int tl = idx >> 6;                 // token 0..15
    const int c8 = (idx & 63) << 3;          // 0..504 step 8
    const uint4 raw = *(const uint4*)(Xb + ((long)(t0 + tl) << 9) + c8);
    float* xr = xs + tl * 516 + c8;
    xr[0] = bf2f((uint16_t)(raw.x & 0xffff)); xr[1] = bf2f((uint16_t)(raw.x >> 16));
    xr[2] = bf2f((uint16_t)(raw.y & 0xffff)); xr[3] = bf2f((uint16_t)(raw.y >> 16));
    xr[4] = bf2f((uint16_t)(raw.z & 0xffff)); xr[5] = bf2f((uint16_t)(raw.z >> 16));
    xr[6] = bf2f((uint16_t)(raw.w & 0xffff)); xr[7] = bf2f((uint16_t)(raw.w >> 16));
  }
  __syncthreads();
  uint8_t* zp = Z + (long)p * 8192;
  for (int e = threadIdx.x; e < 2048; e += 256) {
    const int off = e << 2;            // byte offset in panel
    const int k8 = off >> 7;
    const int tl = (off >> 3) & 15;
    const int c = (k8 << 3) + (off & 4);
    const int t = t0 + tl;
    const float m = S1[t] * (1.f / 512.f);
    const float var = S2[t] * (1.f / 512.f) - m * m;
    const float r = rsqrtf(var + EPS_);
    const float* xr = xs + tl * 516 + c;
    const float v0 = (xr[0] - m) * r * w[c + 0] + bb[c + 0];
    const float v1 = (xr[1] - m) * r * w[c + 1] + bb[c + 1];
    const float v2 = (xr[2] - m) * r * w[c + 2] + bb[c + 2];
    const float v3 = (xr[3] - m) * r * w[c + 3] + bb[c + 3];
    *(int*)(zp + off) = pk_fp8x4(v0, v1, v2, v3);
  }
}

// ---------- fp8 MFMA GEMM: B LDS-resident (64 cols), A direct-global frag-major, barrier-free K-loop ----------
// Grid: blockIdx.x = 64-col group (fastest -> A-tile reuse in L2/L3), blockIdx.y = row tile.
// Block = 4 waves x (MI*16 rows) x 64 cols.
// EPI 0: qkv  -> fp8 token-major (N stride), q-scale for col<512
// EPI 1: proj -> bf16 X1 = x(NCHW) + g1*(acc+b), token-major; fused LN2 raw-sum atomics
// EPI 2: fc1  -> fp8 frag-major (K2=2048) with exact GELU
// EPI 3: fc2  -> f32 NCHW via LDS tile exchange (coalesced); res = X1 bf16 (MI=2: 128 rows)
template<int MI, int K, int EPI>
__global__ __launch_bounds__(256)
void gemm_bl(const uint8_t* __restrict__ A, const uint8_t* __restrict__ Bw,
             const float* __restrict__ bias, const float* __restrict__ res,
             const uint16_t* __restrict__ resb, const float* __restrict__ gamma,
             uint8_t* __restrict__ outb, float* __restrict__ outf,
             uint16_t* __restrict__ outh, float* __restrict__ S1, float* __restrict__ S2,
             const int N) {
  __shared__ uint8_t Bs[33280];     // 32 KB B chunk; EPI3 reuses as 64x130 f32 tile
  const int tid = threadIdx.x;
  const int wave = tid >> 6, lane = tid & 63;
  const int lm = lane & 15, lq = lane >> 4;
  const long m0 = (long)blockIdx.y * (MI * 64);
  const int g = blockIdx.x;                 // 64-col group (fastest-varying)
  const long n0 = (long)g << 6;
  const uint8_t* abase = A + (m0 + wave * MI * 16) * (long)K + (lane << 3);
  floatx4 acc[MI][4] = {};
  constexpr int NKS = K / 32;
  long aC[MI], aN[MI];
  #pragma unroll
  for (int i = 0; i < MI; ++i) aC[i] = *(const long*)(abase + (long)i * 16 * K);
  #pragma unroll
  for (int ph = 0; ph < K / 512; ++ph) {
    const uint8_t* bsrc = Bw + n0 * K + ph * 8192;
    #pragma unroll
    for (int j = 0; j < 4; ++j)
      #pragma unroll
      for (int c = 0; c < 2; ++c)
        gload16(bsrc + (long)j * 16 * K + c * 4096 + tid * 16,
                Bs + j * 8192 + c * 4096 + tid * 16);
    __syncthreads();
    #pragma unroll
    for (int ksl = 0; ksl < 16; ++ksl) {
      const int sg = ph * 16 + ksl;
      if (sg + 1 < NKS) {
        #pragma unroll
        for (int i = 0; i < MI; ++i)
          aN[i] = *(const long*)(abase + (long)i * 16 * K + (sg + 1) * 512);
      }
      long bf[4];
      #pragma unroll
      for (int j = 0; j < 4; ++j)
        bf[j] = *(const long*)(Bs + j * 8192 + ksl * 512 + (lane << 3));
      #pragma unroll
      for (int i = 0; i < MI; ++i)
        #pragma unroll
        for (int j = 0; j < 4; ++j)
          acc[i][j] = __builtin_amdgcn_mfma_f32_16x16x32_fp8_fp8(aC[i], bf[j], acc[i][j], 0, 0, 0);
      #pragma unroll
      for (int i = 0; i < MI; ++i) aC[i] = aN[i];
    }
    if (K / 512 > 1 && ph + 1 < K / 512) __syncthreads();
  }
  const int cb = (g << 6) + (lm << 2);
  const float4 b4 = *(const float4*)(bias + cb);
  float4 g4 = make_float4(0.f, 0.f, 0.f, 0.f);
  if (EPI == 1 || EPI == 3) g4 = *(const float4*)(gamma + cb);
  const float qs = (EPI == 0 && cb < 512) ? QSCALE : 1.f;
  if (EPI != 3) {
    #pragma unroll
    for (int i = 0; i < MI; ++i) {
      #pragma unroll
      for (int r = 0; r < 4; ++r) {
        const long rowg = m0 + wave * MI * 16 + i * 16 + lq * 4 + r;
        float v0 = acc[i][0][r] + b4.x;
        float v1 = acc[i][1][r] + b4.y;
        float v2 = acc[i][2][r] + b4.z;
        float v3 = acc[i][3][r] + b4.w;
        if (EPI == 0) {
          *(int*)(outb + rowg * (long)N + cb) = pk_fp8x4(v0 * qs, v1 * qs, v2 * qs, v3 * qs);
        } else if (EPI == 2) {
          v0 = 0.5f * v0 * (1.f + erff(v0 * 0.70710678118654752f));
          v1 = 0.5f * v1 * (1.f + erff(v1 * 0.70710678118654752f));
          v2 = 0.5f * v2 * (1.f + erff(v2 * 0.70710678118654752f));
          v3 = 0.5f * v3 * (1.f + erff(v3 * 0.70710678118654752f));
          const long addr = (rowg & ~15L) * 2048 + ((cb >> 3) << 7) + ((rowg & 15) << 3) + (cb & 4);
          *(int*)(outb + addr) = pk_fp8x4(v0, v1, v2, v3);
        } else {   // EPI 1
          const unsigned rg = (unsigned)rowg;
          const unsigned bi = rg / 196u;
          const unsigned p = rg - bi * 196u;
          const float* xr = res + (long)bi * 100352 + p;
          const float o0 = xr[(long)(cb + 0) * 196] + g4.x * v0;
          const float o1 = xr[(long)(cb + 1) * 196] + g4.y * v1;
          const float o2 = xr[(long)(cb + 2) * 196] + g4.z * v2;
          const float o3 = xr[(long)(cb + 3) * 196] + g4.w * v3;
          ushort4 hv;
          hv.x = f2bf(o0); hv.y = f2bf(o1); hv.z = f2bf(o2); hv.w = f2bf(o3);
          *(ushort4*)(outh + rowg * 512 + cb) = hv;
          const float q0 = bf2f(hv.x), q1 = bf2f(hv.y), q2 = bf2f(hv.z), q3 = bf2f(hv.w);
          float s = q0 + q1 + q2 + q3;
          float ss = q0 * q0 + q1 * q1 + q2 * q2 + q3 * q3;
          s += __shfl_xor(s, 1);  ss += __shfl_xor(ss, 1);
          s += __shfl_xor(s, 2);  ss += __shfl_xor(ss, 2);
          s += __shfl_xor(s, 4);  ss += __shfl_xor(ss, 4);
          s += __shfl_xor(s, 8);  ss += __shfl_xor(ss, 8);
          if (lm == 0) {
            atomicAdd(S1 + rowg, s);
            atomicAdd(S2 + rowg, ss);
          }
        }
      }
    }
  } else {
    // EPI 3 (MI=2): 128-row tile -> NCHW via LDS exchange, coalesced
    float* T = (float*)Bs;
    __syncthreads();
    #pragma unroll
    for (int i = 0; i < MI; ++i) {
      #pragma unroll
      for (int r = 0; r < 4; ++r) {
        const long rowg = m0 + wave * MI * 16 + i * 16 + lq * 4 + r;
        const int rl = (int)(rowg - m0);   // 0..127
        const ushort4 rb = *(const ushort4*)(resb + rowg * 512 + cb);
        T[(lm * 4 + 0) * 130 + rl] = bf2f(rb.x) + g4.x * (acc[i][0][r] + b4.x);
        T[(lm * 4 + 1) * 130 + rl] = bf2f(rb.y) + g4.y * (acc[i][1][r] + b4.y);
        T[(lm * 4 + 2) * 130 + rl] = bf2f(rb.z) + g4.z * (acc[i][2][r] + b4.z);
        T[(lm * 4 + 3) * 130 + rl] = bf2f(rb.w) + g4.w * (acc[i][3][r] + b4.w);
      }
    }
    __syncthreads();
    #pragma unroll
    for (int t2 = 0; t2 < 32; ++t2) {
      const int idx = t2 * 256 + tid;
      const int rl = idx & 127;
      const int ch = idx >> 7;
      const unsigned m = (unsigned)(m0 + rl);
      const unsigned bi = m / 196u;
      const unsigned p = m - bi * 196u;
      outf[(long)bi * 100352 + (long)(n0 + ch) * 196 + p] = T[ch * 130 + rl];
    }
  }
}

// ---------- BM table: bias+mask+padding in MFMA C-layout order ----------
__global__ __launch_bounds__(256)
void bm_build(const float* __restrict__ rel_bias, float* __restrict__ BM) {
  const int hw = blockIdx.x;           // head*4 + wpos
  const int head = hw >> 2, wpos = hw & 3;
  const int wi = wpos >> 1, wj = wpos & 1;
  for (int k = 0; k < 4; ++k) {
    const int idx = k * 256 + threadIdx.x;   // tile*64 + lane
    const int tile = idx >> 6, l = idx & 63;
    const int qi = tile >> 2, ti = tile & 3;
    const int n = l & 15, g = l >> 4;
    const int query = qi * 16 + n;
    const int qy = query / 7, qx = query - qy * 7;
    const int hh = wi * 7 + qy, ww = wj * 7 + qx;
    const int ri = (hh < 7 ? 0 : (hh < 11 ? 1 : 2)) * 3 + (ww < 7 ? 0 : (ww < 11 ? 1 : 2));
    float4 ov;
    float vv[4];
    #pragma unroll
    for (int r = 0; r < 4; ++r) {
      const int key = ti * 16 + g * 4 + r;
      float v;
      if (query >= 49 || key >= 49) {
        v = -3.0e38f;
      } else {
        const int ky = key / 7, kx = key - ky * 7;
        const int bidx = (qy - ky + 6) * 13 + (qx - kx + 6);
        const int h2 = wi * 7 + ky, w2 = wj * 7 + kx;
        const int rj = (h2 < 7 ? 0 : (h2 < 11 ? 1 : 2)) * 3 + (w2 < 7 ? 0 : (w2 < 11 ? 1 : 2));
        v = rel_bias[bidx * 16 + head] + ((ri != rj) ? -100.f : 0.f);
      }
      vv[r] = v;
    }
    ov.x = vv[0]; ov.y = vv[1]; ov.z = vv[2]; ov.w = vv[3];
    *(float4*)(BM + ((long)(hw * 16 + tile) << 8) + l * 4) = ov;
  }
}

// ---------- 4x4 byte transpose ----------
__device__ __forceinline__ void tr4(const uint32_t d[4], uint32_t o[4]) {
  #pragma unroll
  for (int c = 0; c < 4; ++c)
    o[c] = ((d[0] >> (8 * c)) & 0xffu) | (((d[1] >> (8 * c)) & 0xffu) << 8)
         | (((d[2] >> (8 * c)) & 0xffu) << 16) | (((d[3] >> (8 * c)) & 0xffu) << 24);
}

// ---------- MFMA windowed attention: one wave per (window, head); AT written frag-major ----------
__global__ __launch_bounds__(256)
void attn_mfma(const uint8_t* __restrict__ QKV, const float* __restrict__ BM,
               uint8_t* __restrict__ AT) {
  __shared__ uint8_t lds[4][9984];   // per-wave: Pb 64x72, Vt 32x72, Ot 64x48
  const int wave = threadIdx.x >> 6, lane = threadIdx.x & 63;
  const int n = lane & 15, g = lane >> 4;
  const int gw = blockIdx.x * 4 + wave;
  const int wd = gw >> 4, head = gw & 15;
  const int b = wd >> 2, wpos = wd & 3;
  const int wi = wpos >> 1, wj = wpos & 1;
  uint8_t* Pb = lds[wave];
  uint8_t* Vt = lds[wave] + 4608;
  uint8_t* Ot = lds[wave] + 6912;
  const long base = (long)b * 196 * 1536;
  auto tok = [&](int slot) -> int {
    const int ty = slot / 7, tx = slot - ty * 7;
    int h = wi * 7 + ty + 3; if (h >= 14) h -= 14;
    int w = wj * 7 + tx + 3; if (w >= 14) w -= 14;
    return h * 14 + w;
  };
  long Ak[4], Bq[4];
  #pragma unroll
  for (int t4 = 0; t4 < 4; ++t4) {
    int slot = t4 * 16 + n; if (slot > 48) slot = 48;
    const long tb = base + (long)tok(slot) * 1536 + head * 32 + g * 8;
    Bq[t4] = *(const long*)(QKV + tb);          // Q rows (B operand)
    Ak[t4] = *(const long*)(QKV + tb + 512);    // K rows (A operand)
  }
  #pragma unroll
  for (int bb2 = 0; bb2 < 2; ++bb2) {
    const int blk = lane + bb2 * 64;
    const int dq = blk >> 4, tq = blk & 15;
    uint32_t d4[4], o4[4];
    #pragma unroll
    for (int r = 0; r < 4; ++r) {
      int slot = tq * 4 + r; if (slot > 48) slot = 48;
      d4[r] = *(const uint32_t*)(QKV + base + (long)tok(slot) * 1536 + 1024 + head * 32 + dq * 4);
    }
    tr4(d4, o4);
    #pragma unroll
    for (int c = 0; c < 4; ++c)
      *(uint32_t*)(Vt + (dq * 4 + c) * 72 + tq * 4) = o4[c];
  }
  floatx4 acc[4][4];
  const float* bmw = BM + ((long)(head * 4 + wpos) << 12) + lane * 4;
  #pragma unroll
  for (int qi = 0; qi < 4; ++qi)
    #pragma unroll
    for (int ti = 0; ti < 4; ++ti) {
      const float4 bv = *(const float4*)(bmw + ((qi * 4 + ti) << 8));
      acc[qi][ti][0] = bv.x; acc[qi][ti][1] = bv.y;
      acc[qi][ti][2] = bv.z; acc[qi][ti][3] = bv.w;
    }
  #pragma unroll
  for (int qi = 0; qi < 4; ++qi)
    #pragma unroll
    for (int ti = 0; ti < 4; ++ti)
      acc[qi][ti] = __builtin_amdgcn_mfma_f32_16x16x32_fp8_fp8(Ak[ti], Bq[qi], acc[qi][ti], 0, 0, 0);
  #pragma unroll
  for (int qi = 0; qi < 4; ++qi) {
    float mx = -3.0e38f;
    #pragma unroll
    for (int ti = 0; ti < 4; ++ti)
      #pragma unroll
      for (int r = 0; r < 4; ++r) mx = fmaxf(mx, acc[qi][ti][r]);
    mx = fmaxf(mx, __shfl_xor(mx, 16));
    mx = fmaxf(mx, __shfl_xor(mx, 32));
    float sum = 0.f;
    #pragma unroll
    for (int ti = 0; ti < 4; ++ti)
      #pragma unroll
      for (int r = 0; r < 4; ++r) {
        const float e = __expf(acc[qi][ti][r] - mx);
        acc[qi][ti][r] = e; sum += e;
      }
    sum += __shfl_xor(sum, 16);
    sum += __shfl_xor(sum, 32);
    const float inv = 1.f / sum;
    #pragma unroll
    for (int ti = 0; ti < 4; ++ti) {
      const int pw = pk_fp8x4(acc[qi][ti][0] * inv, acc[qi][ti][1] * inv,
                              acc[qi][ti][2] * inv, acc[qi][ti][3] * inv);
      *(uint32_t*)(Pb + (qi * 16 + n) * 72 + ti * 16 + g * 4) = pw;
    }
  }
  asm volatile("s_waitcnt lgkmcnt(0)" ::: "memory");
  long Bv[2][2];
  #pragma unroll
  for (int ni = 0; ni < 2; ++ni)
    #pragma unroll
    for (int s = 0; s < 2; ++s)
      Bv[ni][s] = *(const long*)(Vt + (ni * 16 + n) * 72 + s * 32 + g * 8);
  floatx4 o[4][2] = {};
  #pragma unroll
  for (int qi = 0; qi < 4; ++qi)
    #pragma unroll
    for (int s = 0; s < 2; ++s) {
      const long Ap = *(const long*)(Pb + (qi * 16 + n) * 72 + s * 32 + g * 8);
      #pragma unroll
      for (int ni = 0; ni < 2; ++ni)
        o[qi][ni] = __builtin_amdgcn_mfma_f32_16x16x32_fp8_fp8(Ap, Bv[ni][s], o[qi][ni], 0, 0, 0);
    }
  #pragma unroll
  for (int qi = 0; qi < 4; ++qi)
    #pragma unroll
    for (int ni = 0; ni < 2; ++ni)
      #pragma unroll
      for (int r = 0; r < 4; ++r)
        Ot[(qi * 16 + g * 4 + r) * 48 + ni * 16 + n] =
            (uint8_t)(pk_fp8<false>(o[qi][ni][r], 0.f, 0) & 0xff);
  asm volatile("s_waitcnt lgkmcnt(0)" ::: "memory");
  if (lane < 49) {
    const int m = b * 196 + tok(lane);
    uint8_t* opb = AT + (long)(m & ~15) * 512 + ((m & 15) << 3);
    #pragma unroll
    for (int d8 = 0; d8 < 4; ++d8)
      *(long*)(opb + (head * 4 + d8) * 128) = *(const long*)(Ot + lane * 48 + d8 * 8);
  }
}

extern "C" void kernel_launch(void* const* d_in, const int* in_sizes, int n_in,
                              void* d_out, int out_size, void* d_ws, size_t ws_size,
                              hipStream_t stream) {
  const float* x      = (const float*)d_in[0];
  const float* ln1_w  = (const float*)d_in[1];
  const float* ln1_b  = (const float*)d_in[2];
  const float* qkv_w  = (const float*)d_in[3];
  const float* qkv_b  = (const float*)d_in[4];
  const float* relb   = (const float*)d_in[5];
  const float* proj_w = (const float*)d_in[6];
  const float* proj_b = (const float*)d_in[7];
  const float* gamma1 = (const float*)d_in[8];
  const float* ln2_w  = (const float*)d_in[9];
  const float* ln2_b  = (const float*)d_in[10];
  const float* fc1_w  = (const float*)d_in[11];
  const float* fc1_b  = (const float*)d_in[12];
  const float* fc2_w  = (const float*)d_in[13];
  const float* fc2_b  = (const float*)d_in[14];
  const float* gamma2 = (const float*)d_in[15];
  float* out = (float*)d_out;
  char* ws = (char*)d_ws;

  float*    mu1 = (float*)(ws + 0);
  float*    rs1 = (float*)(ws + 100352);
  float*    S1  = (float*)(ws + 200704);      // LN2 raw sum
  float*    S2  = (float*)(ws + 301056);      // LN2 raw sumsq
  uint8_t*  Wq  = (uint8_t*)(ws + 401408);    //   786,432 B frag-major
  uint8_t*  Wp  = (uint8_t*)(ws + 1187840);   //   262,144 B
  uint8_t*  W1  = (uint8_t*)(ws + 1449984);   // 1,048,576 B
  uint8_t*  W2  = (uint8_t*)(ws + 2498560);   // 1,048,576 B
  float*    BMt = (float*)  (ws + 3547136);   // 1,048,576 B bias+mask table
  uint8_t*  Afp = (uint8_t*)(ws + 4595712);   // 12,845,056 B frag-major tokens (LN1, later LN2)
  uint16_t* X1b = (uint16_t*)(ws + 68820992); // 25,690,112 B token-major bf16
  uint8_t*  QKV = (uint8_t*)(ws + 120201216); // 38,535,168 B token-major fp8
  uint8_t*  AT  = (uint8_t*)(ws + 158736384); // 12,845,056 B frag-major fp8
  uint8_t*  Hb  = (uint8_t*)(ws + 120201216); // 51,380,224 B frag-major, overlaps dead QKV+AT

  // zero LN2 sum buffers (atomics accumulate during proj epilogue)
  hipMemsetAsync(ws + 200704, 0, 200704, stream);

  // weights -> fp8 frag-major, BM table
  cvt_frag<512> <<<768,  256, 0, stream>>>(qkv_w, Wq, 196608);
  cvt_frag<512> <<<256,  256, 0, stream>>>(proj_w, Wp, 65536);
  cvt_frag<512> <<<1024, 256, 0, stream>>>(fc1_w, W1, 262144);
  cvt_frag<2048><<<1024, 256, 0, stream>>>(fc2_w, W2, 262144);
  bm_build<<<64, 256, 0, stream>>>(relb, BMt);

  // LN1 -> frag-major fp8 tokens
  ln_stats_nchw<<<392, 256, 0, stream>>>(x, mu1, rs1);
  ln1_apply<<<4096, 256, 0, stream>>>(x, mu1, rs1, ln1_w, ln1_b, Afp);

  // qkv GEMM (q pre-scaled), token-major QKV out   [col-group fastest]
  gemm_bl<4, 512, 0><<<dim3(24, 98), 256, 0, stream>>>(Afp, Wq, qkv_b, nullptr, nullptr, nullptr, QKV, nullptr, nullptr, nullptr, nullptr, 1536);

  // shifted-window attention (MFMA), frag-major AT out
  attn_mfma<<<2048, 256, 0, stream>>>(QKV, BMt, AT);

  // proj GEMM: X1b(bf16) = x(NCHW) + g1*(out+b); fused LN2 stats
  gemm_bl<4, 512, 1><<<dim3(8, 98), 256, 0, stream>>>(AT, Wp, proj_b, x, nullptr, gamma1, nullptr, nullptr, X1b, S1, S2, 512);

  // LN2 apply -> frag-major fp8 tokens
  ln2_panel<<<1568, 256, 0, stream>>>(X1b, S1, S2, ln2_w, ln2_b, Afp);

  // MLP: fc1 -> frag-major Hb (gelu); fc2 -> NCHW out via LDS exchange
  gemm_bl<4, 512, 2><<<dim3(32, 98), 256, 0, stream>>>(Afp, W1, fc1_b, nullptr, nullptr, nullptr, Hb, nullptr, nullptr, nullptr, nullptr, 2048);
  gemm_bl<2, 2048, 3><<<dim3(8, 196), 256, 0, stream>>>(Hb, W2, fc2_b, nullptr, X1b, gamma2, nullptr, out, nullptr, nullptr, nullptr, 512);
}

// Round 10
// 396.091 us; speedup vs baseline: 1.8148x; 1.0876x over previous
//
#include <hip/hip_runtime.h>
#include <cmath>
#include <cstdint>

typedef float floatx4 __attribute__((ext_vector_type(4)));

#define EPS_ 1e-5f
#define QSCALE 0.17677669529663689f

// ---------- async global->LDS (16B per lane) ----------
__device__ __forceinline__ void gload16(const uint8_t* g, uint8_t* l) {
  __builtin_amdgcn_global_load_lds(
      (const __attribute__((address_space(1))) void*)g,
      (__attribute__((address_space(3))) void*)l, 16, 0, 0);
}

// ---------- fp8 e4m3 pack (word-select must be an immediate) ----------
template<bool HI>
__device__ __forceinline__ int pk_fp8(float a, float b, int old) {
  return __builtin_amdgcn_cvt_pk_fp8_f32(a, b, old, HI);
}
__device__ __forceinline__ int pk_fp8x4(float v0, float v1, float v2, float v3) {
  int w = pk_fp8<false>(v0, v1, 0);
  return pk_fp8<true>(v2, v3, w);
}

// ---------- bf16 helpers (RNE) ----------
__device__ __forceinline__ uint16_t f2bf(float f) {
  uint32_t u = __float_as_uint(f);
  return (uint16_t)((u + 0x7fffu + ((u >> 16) & 1u)) >> 16);
}
__device__ __forceinline__ float bf2f(uint16_t h) {
  return __uint_as_float(((uint32_t)h) << 16);
}

// Fragment-major layout for all GEMM operands:
//   addr(m, k) = (m & ~15)*K + (k>>3)*128 + (m & 15)*8 + (k & 7)

// ---------- fp32 weights -> fp8 frag-major (col-permuted: panel 4g+j slot lm = col 64g+4lm+j) ----------
template<int K>
__global__ void cvt_frag(const float* __restrict__ s, uint8_t* __restrict__ d, int n4) {
  const int i = blockIdx.x * 256 + threadIdx.x;
  if (i >= n4) return;
  const int kq = K >> 2;
  const int n = i / kq;
  const int k = (i - n * kq) << 2;
  const float4 v = ((const float4*)s)[i];
  const int panel = ((n >> 6) << 2) + (n & 3);
  const int lm = (n >> 2) & 15;
  const long addr = (long)panel * (16 * K) + ((k >> 3) << 7) + (lm << 3) + (k & 4);
  *(int*)(d + addr) = pk_fp8x4(v.x, v.y, v.z, v.w);
}

// ---------- LN1 stats over C for NCHW input ----------
__global__ __launch_bounds__(256)
void ln_stats_nchw(const float* __restrict__ x, float* __restrict__ mu, float* __restrict__ rs) {
  const int tl = threadIdx.x & 63;
  const int wv = threadIdx.x >> 6;
  const int t = blockIdx.x * 64 + tl;       // token = b*196 + p
  const int b = t / 196;
  const int p = t - b * 196;
  const float* xp = x + (long)b * 100352 + p;
  float s = 0.f, ss = 0.f;
  const int cbeg = wv * 128;
  for (int c = cbeg; c < cbeg + 128; ++c) {
    const float v = xp[(long)c * 196];
    s += v; ss += v * v;
  }
  __shared__ float sb[4][64], qb[4][64];
  sb[wv][tl] = s; qb[wv][tl] = ss;
  __syncthreads();
  if (wv == 0) {
    s  = sb[0][tl] + sb[1][tl] + sb[2][tl] + sb[3][tl];
    ss = qb[0][tl] + qb[1][tl] + qb[2][tl] + qb[3][tl];
    const float m = s * (1.f / 512.f);
    const float var = ss * (1.f / 512.f) - m * m;
    mu[t] = m;
    rs[t] = rsqrtf(var + EPS_);
  }
}

// ---------- LN1 apply: NCHW -> frag-major fp8 tokens ----------
__global__ __launch_bounds__(256)
void ln1_apply(const float* __restrict__ x, const float* __restrict__ mu, const float* __restrict__ rs,
               const float* __restrict__ w, const float* __restrict__ bb, uint8_t* __restrict__ A) {
  __shared__ float tile[64][53];
  const int bid = blockIdx.x;
  const int ct = bid & 7;
  const int pt = (bid >> 3) & 3;
  const int b = bid >> 5;
  const int p0 = pt * 49, c0 = ct * 64;
  const long xbase = (long)b * 100352;
  for (int idx = threadIdx.x; idx < 3136; idx += 256) {
    const int cl = idx / 49;
    const int pl = idx - cl * 49;
    tile[cl][pl] = x[xbase + (long)(c0 + cl) * 196 + p0 + pl];
  }
  __syncthreads();
  const int tbase = b * 196 + p0;
  for (int idx = threadIdx.x; idx < 784; idx += 256) {
    const int pl = idx >> 4;                // 0..48
    const int cq = (idx & 15) << 2;         // 0..60 step 4
    const int t = tbase + pl;
    const int c = c0 + cq;
    const float m = mu[t], rr = rs[t];
    const float v0 = (tile[cq + 0][pl] - m) * rr * w[c + 0] + bb[c + 0];
    const float v1 = (tile[cq + 1][pl] - m) * rr * w[c + 1] + bb[c + 1];
    const float v2 = (tile[cq + 2][pl] - m) * rr * w[c + 2] + bb[c + 2];
    const float v3 = (tile[cq + 3][pl] - m) * rr * w[c + 3] + bb[c + 3];
    const long addr = (long)(t & ~15) * 512 + ((c >> 3) << 7) + ((t & 15) << 3) + (c & 4);
    *(int*)(A + addr) = pk_fp8x4(v0, v1, v2, v3);
  }
}

// ---------- LN2: one block per 16-token panel; X1 bf16 -> frag-major fp8 ----------
__global__ __launch_bounds__(256)
void ln2_panel(const uint16_t* __restrict__ Xb, const float* __restrict__ S1,
               const float* __restrict__ S2, const float* __restrict__ w,
               const float* __restrict__ bb, uint8_t* __restrict__ Z) {
  __shared__ float xs[16 * 516];
  const int p = blockIdx.x;
  const int t0 = p * 16;
  for (int idx = threadIdx.x; idx < 1024; idx += 256) {
    const int tl = idx >> 6;                 // token 0..15
    const int c8 = (idx & 63) << 3;          // 0..504 step 8
    const uint4 raw = *(const uint4*)(Xb + ((long)(t0 + tl) << 9) + c8);
    float* xr = xs + tl * 516 + c8;
    xr[0] = bf2f((uint16_t)(raw.x & 0xffff)); xr[1] = bf2f((uint16_t)(raw.x >> 16));
    xr[2] = bf2f((uint16_t)(raw.y & 0xffff)); xr[3] = bf2f((uint16_t)(raw.y >> 16));
    xr[4] = bf2f((uint16_t)(raw.z & 0xffff)); xr[5] = bf2f((uint16_t)(raw.z >> 16));
    xr[6] = bf2f((uint16_t)(raw.w & 0xffff)); xr[7] = bf2f((uint16_t)(raw.w >> 16));
  }
  __syncthreads();
  uint8_t* zp = Z + (long)p * 8192;
  for (int e = threadIdx.x; e < 2048; e += 256) {
    const int off = e << 2;            // byte offset in panel
    const int k8 = off >> 7;
    const int tl = (off >> 3) & 15;
    const int c = (k8 << 3) + (off & 4);
    const int t = t0 + tl;
    const float m = S1[t] * (1.f / 512.f);
    const float var = S2[t] * (1.f / 512.f) - m * m;
    const float r = rsqrtf(var + EPS_);
    const float* xr = xs + tl * 516 + c;
    const float v0 = (xr[0] - m) * r * w[c + 0] + bb[c + 0];
    const float v1 = (xr[1] - m) * r * w[c + 1] + bb[c + 1];
    const float v2 = (xr[2] - m) * r * w[c + 2] + bb[c + 2];
    const float v3 = (xr[3] - m) * r * w[c + 3] + bb[c + 3];
    *(int*)(zp + off) = pk_fp8x4(v0, v1, v2, v3);
  }
}

// ---------- fp8 MFMA GEMM: B LDS-resident (64 cols), A direct-global frag-major, barrier-free K-loop ----------
// XCD-aware swizzled 1-D grid: k = blockIdx.x & 7 (XCD via i%8 heuristic), s = blockIdx.x >> 3,
// tile t = (s/NG)*8 + k, col group c = s%NG  => all NG col blocks of a tile on ONE XCD (A fetched once).
// Block = 4 waves x (MI*16 rows) x 64 cols.
// EPI 0: qkv  -> fp8 token-major (N stride), q-scale for col<512
// EPI 1: proj -> bf16 X1 = x(NCHW) + g1*(acc+b), token-major; fused LN2 raw-sum atomics
// EPI 2: fc1  -> fp8 frag-major (K2=2048) with exact GELU
// EPI 3: fc2  -> f32 NCHW via LDS tile exchange (coalesced); res = X1 bf16 (MI=2: 128 rows)
template<int MI, int K, int EPI, int NG, int T>
__global__ __launch_bounds__(256)
void gemm_bl(const uint8_t* __restrict__ A, const uint8_t* __restrict__ Bw,
             const float* __restrict__ bias, const float* __restrict__ res,
             const uint16_t* __restrict__ resb, const float* __restrict__ gamma,
             uint8_t* __restrict__ outb, float* __restrict__ outf,
             uint16_t* __restrict__ outh, float* __restrict__ S1, float* __restrict__ S2,
             const int N) {
  const int kx = blockIdx.x & 7;
  const int sx = blockIdx.x >> 3;
  const int t = (sx / NG) * 8 + kx;
  if (t >= T) return;
  const int g = sx - (sx / NG) * NG;        // 64-col group
  __shared__ uint8_t Bs[33280];     // 32 KB B chunk; EPI3 reuses as 64x129 f32 tile
  const int tid = threadIdx.x;
  const int wave = tid >> 6, lane = tid & 63;
  const int lm = lane & 15, lq = lane >> 4;
  const long m0 = (long)t * (MI * 64);
  const long n0 = (long)g << 6;
  const uint8_t* abase = A + (m0 + wave * MI * 16) * (long)K + (lane << 3);
  floatx4 acc[MI][4] = {};
  constexpr int NKS = K / 32;
  long aC[MI], aN[MI];
  #pragma unroll
  for (int i = 0; i < MI; ++i) aC[i] = *(const long*)(abase + (long)i * 16 * K);
  #pragma unroll
  for (int ph = 0; ph < K / 512; ++ph) {
    const uint8_t* bsrc = Bw + n0 * K + ph * 8192;
    #pragma unroll
    for (int j = 0; j < 4; ++j)
      #pragma unroll
      for (int c = 0; c < 2; ++c)
        gload16(bsrc + (long)j * 16 * K + c * 4096 + tid * 16,
                Bs + j * 8192 + c * 4096 + tid * 16);
    __syncthreads();
    #pragma unroll
    for (int ksl = 0; ksl < 16; ++ksl) {
      const int sg = ph * 16 + ksl;
      if (sg + 1 < NKS) {
        #pragma unroll
        for (int i = 0; i < MI; ++i)
          aN[i] = *(const long*)(abase + (long)i * 16 * K + (sg + 1) * 512);
      }
      long bf[4];
      #pragma unroll
      for (int j = 0; j < 4; ++j)
        bf[j] = *(const long*)(Bs + j * 8192 + ksl * 512 + (lane << 3));
      #pragma unroll
      for (int i = 0; i < MI; ++i)
        #pragma unroll
        for (int j = 0; j < 4; ++j)
          acc[i][j] = __builtin_amdgcn_mfma_f32_16x16x32_fp8_fp8(aC[i], bf[j], acc[i][j], 0, 0, 0);
      #pragma unroll
      for (int i = 0; i < MI; ++i) aC[i] = aN[i];
    }
    if (K / 512 > 1 && ph + 1 < K / 512) __syncthreads();
  }
  const int cb = (g << 6) + (lm << 2);
  const float4 b4 = *(const float4*)(bias + cb);
  float4 g4 = make_float4(0.f, 0.f, 0.f, 0.f);
  if (EPI == 1 || EPI == 3) g4 = *(const float4*)(gamma + cb);
  const float qs = (EPI == 0 && cb < 512) ? QSCALE : 1.f;
  if (EPI != 3) {
    #pragma unroll
    for (int i = 0; i < MI; ++i) {
      #pragma unroll
      for (int r = 0; r < 4; ++r) {
        const long rowg = m0 + wave * MI * 16 + i * 16 + lq * 4 + r;
        float v0 = acc[i][0][r] + b4.x;
        float v1 = acc[i][1][r] + b4.y;
        float v2 = acc[i][2][r] + b4.z;
        float v3 = acc[i][3][r] + b4.w;
        if (EPI == 0) {
          *(int*)(outb + rowg * (long)N + cb) = pk_fp8x4(v0 * qs, v1 * qs, v2 * qs, v3 * qs);
        } else if (EPI == 2) {
          v0 = 0.5f * v0 * (1.f + erff(v0 * 0.70710678118654752f));
          v1 = 0.5f * v1 * (1.f + erff(v1 * 0.70710678118654752f));
          v2 = 0.5f * v2 * (1.f + erff(v2 * 0.70710678118654752f));
          v3 = 0.5f * v3 * (1.f + erff(v3 * 0.70710678118654752f));
          const long addr = (rowg & ~15L) * 2048 + ((cb >> 3) << 7) + ((rowg & 15) << 3) + (cb & 4);
          *(int*)(outb + addr) = pk_fp8x4(v0, v1, v2, v3);
        } else {   // EPI 1
          const unsigned rg = (unsigned)rowg;
          const unsigned bi = rg / 196u;
          const unsigned p = rg - bi * 196u;
          const float* xr = res + (long)bi * 100352 + p;
          const float o0 = xr[(long)(cb + 0) * 196] + g4.x * v0;
          const float o1 = xr[(long)(cb + 1) * 196] + g4.y * v1;
          const float o2 = xr[(long)(cb + 2) * 196] + g4.z * v2;
          const float o3 = xr[(long)(cb + 3) * 196] + g4.w * v3;
          ushort4 hv;
          hv.x = f2bf(o0); hv.y = f2bf(o1); hv.z = f2bf(o2); hv.w = f2bf(o3);
          *(ushort4*)(outh + rowg * 512 + cb) = hv;
          const float q0 = bf2f(hv.x), q1 = bf2f(hv.y), q2 = bf2f(hv.z), q3 = bf2f(hv.w);
          float s = q0 + q1 + q2 + q3;
          float ss = q0 * q0 + q1 * q1 + q2 * q2 + q3 * q3;
          s += __shfl_xor(s, 1);  ss += __shfl_xor(ss, 1);
          s += __shfl_xor(s, 2);  ss += __shfl_xor(ss, 2);
          s += __shfl_xor(s, 4);  ss += __shfl_xor(ss, 4);
          s += __shfl_xor(s, 8);  ss += __shfl_xor(ss, 8);
          if (lm == 0) {
            atomicAdd(S1 + rowg, s);
            atomicAdd(S2 + rowg, ss);
          }
        }
      }
    }
  } else {
    // EPI 3 (MI=2): 128-row tile -> NCHW via LDS exchange, coalesced (stride 129: 2-way = free)
    float* Tx = (float*)Bs;
    __syncthreads();
    #pragma unroll
    for (int i = 0; i < MI; ++i) {
      #pragma unroll
      for (int r = 0; r < 4; ++r) {
        const long rowg = m0 + wave * MI * 16 + i * 16 + lq * 4 + r;
        const int rl = (int)(rowg - m0);   // 0..127
        const ushort4 rb = *(const ushort4*)(resb + rowg * 512 + cb);
        Tx[(lm * 4 + 0) * 129 + rl] = bf2f(rb.x) + g4.x * (acc[i][0][r] + b4.x);
        Tx[(lm * 4 + 1) * 129 + rl] = bf2f(rb.y) + g4.y * (acc[i][1][r] + b4.y);
        Tx[(lm * 4 + 2) * 129 + rl] = bf2f(rb.z) + g4.z * (acc[i][2][r] + b4.z);
        Tx[(lm * 4 + 3) * 129 + rl] = bf2f(rb.w) + g4.w * (acc[i][3][r] + b4.w);
      }
    }
    __syncthreads();
    #pragma unroll
    for (int t2 = 0; t2 < 32; ++t2) {
      const int idx = t2 * 256 + tid;
      const int rl = idx & 127;
      const int ch = idx >> 7;
      const unsigned m = (unsigned)(m0 + rl);
      const unsigned bi = m / 196u;
      const unsigned p = m - bi * 196u;
      outf[(long)bi * 100352 + (long)(n0 + ch) * 196 + p] = Tx[ch * 129 + rl];
    }
  }
}

// ---------- BM table: bias+mask+padding in MFMA C-layout order ----------
__global__ __launch_bounds__(256)
void bm_build(const float* __restrict__ rel_bias, float* __restrict__ BM) {
  const int hw = blockIdx.x;           // head*4 + wpos
  const int head = hw >> 2, wpos = hw & 3;
  const int wi = wpos >> 1, wj = wpos & 1;
  for (int k = 0; k < 4; ++k) {
    const int idx = k * 256 + threadIdx.x;   // tile*64 + lane
    const int tile = idx >> 6, l = idx & 63;
    const int qi = tile >> 2, ti = tile & 3;
    const int n = l & 15, g = l >> 4;
    const int query = qi * 16 + n;
    const int qy = query / 7, qx = query - qy * 7;
    const int hh = wi * 7 + qy, ww = wj * 7 + qx;
    const int ri = (hh < 7 ? 0 : (hh < 11 ? 1 : 2)) * 3 + (ww < 7 ? 0 : (ww < 11 ? 1 : 2));
    float4 ov;
    float vv[4];
    #pragma unroll
    for (int r = 0; r < 4; ++r) {
      const int key = ti * 16 + g * 4 + r;
      float v;
      if (query >= 49 || key >= 49) {
        v = -3.0e38f;
      } else {
        const int ky = key / 7, kx = key - ky * 7;
        const int bidx = (qy - ky + 6) * 13 + (qx - kx + 6);
        const int h2 = wi * 7 + ky, w2 = wj * 7 + kx;
        const int rj = (h2 < 7 ? 0 : (h2 < 11 ? 1 : 2)) * 3 + (w2 < 7 ? 0 : (w2 < 11 ? 1 : 2));
        v = rel_bias[bidx * 16 + head] + ((ri != rj) ? -100.f : 0.f);
      }
      vv[r] = v;
    }
    ov.x = vv[0]; ov.y = vv[1]; ov.z = vv[2]; ov.w = vv[3];
    *(float4*)(BM + ((long)(hw * 16 + tile) << 8) + l * 4) = ov;
  }
}

// ---------- 4x4 byte transpose ----------
__device__ __forceinline__ void tr4(const uint32_t d[4], uint32_t o[4]) {
  #pragma unroll
  for (int c = 0; c < 4; ++c)
    o[c] = ((d[0] >> (8 * c)) & 0xffu) | (((d[1] >> (8 * c)) & 0xffu) << 8)
         | (((d[2] >> (8 * c)) & 0xffu) << 16) | (((d[3] >> (8 * c)) & 0xffu) << 24);
}

// ---------- MFMA windowed attention: one wave per (window, head); AT written frag-major ----------
__global__ __launch_bounds__(256)
void attn_mfma(const uint8_t* __restrict__ QKV, const float* __restrict__ BM,
               uint8_t* __restrict__ AT) {
  __shared__ uint8_t lds[4][9984];   // per-wave: Pb 64x72, Vt 32x72, Ot 64x48
  const int wave = threadIdx.x >> 6, lane = threadIdx.x & 63;
  const int n = lane & 15, g = lane >> 4;
  const int gw = blockIdx.x * 4 + wave;
  const int wd = gw >> 4, head = gw & 15;
  const int b = wd >> 2, wpos = wd & 3;
  const int wi = wpos >> 1, wj = wpos & 1;
  uint8_t* Pb = lds[wave];
  uint8_t* Vt = lds[wave] + 4608;
  uint8_t* Ot = lds[wave] + 6912;
  const long base = (long)b * 196 * 1536;
  auto tok = [&](int slot) -> int {
    const int ty = slot / 7, tx = slot - ty * 7;
    int h = wi * 7 + ty + 3; if (h >= 14) h -= 14;
    int w = wj * 7 + tx + 3; if (w >= 14) w -= 14;
    return h * 14 + w;
  };
  long Ak[4], Bq[4];
  #pragma unroll
  for (int t4 = 0; t4 < 4; ++t4) {
    int slot = t4 * 16 + n; if (slot > 48) slot = 48;
    const long tb = base + (long)tok(slot) * 1536 + head * 32 + g * 8;
    Bq[t4] = *(const long*)(QKV + tb);          // Q rows (B operand)
    Ak[t4] = *(const long*)(QKV + tb + 512);    // K rows (A operand)
  }
  #pragma unroll
  for (int bb2 = 0; bb2 < 2; ++bb2) {
    const int blk = lane + bb2 * 64;
    const int dq = blk >> 4, tq = blk & 15;
    uint32_t d4[4], o4[4];
    #pragma unroll
    for (int r = 0; r < 4; ++r) {
      int slot = tq * 4 + r; if (slot > 48) slot = 48;
      d4[r] = *(const uint32_t*)(QKV + base + (long)tok(slot) * 1536 + 1024 + head * 32 + dq * 4);
    }
    tr4(d4, o4);
    #pragma unroll
    for (int c = 0; c < 4; ++c)
      *(uint32_t*)(Vt + (dq * 4 + c) * 72 + tq * 4) = o4[c];
  }
  floatx4 acc[4][4];
  const float* bmw = BM + ((long)(head * 4 + wpos) << 12) + lane * 4;
  #pragma unroll
  for (int qi = 0; qi < 4; ++qi)
    #pragma unroll
    for (int ti = 0; ti < 4; ++ti) {
      const float4 bv = *(const float4*)(bmw + ((qi * 4 + ti) << 8));
      acc[qi][ti][0] = bv.x; acc[qi][ti][1] = bv.y;
      acc[qi][ti][2] = bv.z; acc[qi][ti][3] = bv.w;
    }
  #pragma unroll
  for (int qi = 0; qi < 4; ++qi)
    #pragma unroll
    for (int ti = 0; ti < 4; ++ti)
      acc[qi][ti] = __builtin_amdgcn_mfma_f32_16x16x32_fp8_fp8(Ak[ti], Bq[qi], acc[qi][ti], 0, 0, 0);
  #pragma unroll
  for (int qi = 0; qi < 4; ++qi) {
    float mx = -3.0e38f;
    #pragma unroll
    for (int ti = 0; ti < 4; ++ti)
      #pragma unroll
      for (int r = 0; r < 4; ++r) mx = fmaxf(mx, acc[qi][ti][r]);
    mx = fmaxf(mx, __shfl_xor(mx, 16));
    mx = fmaxf(mx, __shfl_xor(mx, 32));
    float sum = 0.f;
    #pragma unroll
    for (int ti = 0; ti < 4; ++ti)
      #pragma unroll
      for (int r = 0; r < 4; ++r) {
        const float e = __expf(acc[qi][ti][r] - mx);
        acc[qi][ti][r] = e; sum += e;
      }
    sum += __shfl_xor(sum, 16);
    sum += __shfl_xor(sum, 32);
    const float inv = 1.f / sum;
    #pragma unroll
    for (int ti = 0; ti < 4; ++ti) {
      const int pw = pk_fp8x4(acc[qi][ti][0] * inv, acc[qi][ti][1] * inv,
                              acc[qi][ti][2] * inv, acc[qi][ti][3] * inv);
      *(uint32_t*)(Pb + (qi * 16 + n) * 72 + ti * 16 + g * 4) = pw;
    }
  }
  asm volatile("s_waitcnt lgkmcnt(0)" ::: "memory");
  long Bv[2][2];
  #pragma unroll
  for (int ni = 0; ni < 2; ++ni)
    #pragma unroll
    for (int s = 0; s < 2; ++s)
      Bv[ni][s] = *(const long*)(Vt + (ni * 16 + n) * 72 + s * 32 + g * 8);
  floatx4 o[4][2] = {};
  #pragma unroll
  for (int qi = 0; qi < 4; ++qi)
    #pragma unroll
    for (int s = 0; s < 2; ++s) {
      const long Ap = *(const long*)(Pb + (qi * 16 + n) * 72 + s * 32 + g * 8);
      #pragma unroll
      for (int ni = 0; ni < 2; ++ni)
        o[qi][ni] = __builtin_amdgcn_mfma_f32_16x16x32_fp8_fp8(Ap, Bv[ni][s], o[qi][ni], 0, 0, 0);
    }
  #pragma unroll
  for (int qi = 0; qi < 4; ++qi)
    #pragma unroll
    for (int ni = 0; ni < 2; ++ni)
      #pragma unroll
      for (int r = 0; r < 4; ++r)
        Ot[(qi * 16 + g * 4 + r) * 48 + ni * 16 + n] =
            (uint8_t)(pk_fp8<false>(o[qi][ni][r], 0.f, 0) & 0xff);
  asm volatile("s_waitcnt lgkmcnt(0)" ::: "memory");
  if (lane < 49) {
    const int m = b * 196 + tok(lane);
    uint8_t* opb = AT + (long)(m & ~15) * 512 + ((m & 15) << 3);
    #pragma unroll
    for (int d8 = 0; d8 < 4; ++d8)
      *(long*)(opb + (head * 4 + d8) * 128) = *(const long*)(Ot + lane * 48 + d8 * 8);
  }
}

extern "C" void kernel_launch(void* const* d_in, const int* in_sizes, int n_in,
                              void* d_out, int out_size, void* d_ws, size_t ws_size,
                              hipStream_t stream) {
  const float* x      = (const float*)d_in[0];
  const float* ln1_w  = (const float*)d_in[1];
  const float* ln1_b  = (const float*)d_in[2];
  const float* qkv_w  = (const float*)d_in[3];
  const float* qkv_b  = (const float*)d_in[4];
  const float* relb   = (const float*)d_in[5];
  const float* proj_w = (const float*)d_in[6];
  const float* proj_b = (const float*)d_in[7];
  const float* gamma1 = (const float*)d_in[8];
  const float* ln2_w  = (const float*)d_in[9];
  const float* ln2_b  = (const float*)d_in[10];
  const float* fc1_w  = (const float*)d_in[11];
  const float* fc1_b  = (const float*)d_in[12];
  const float* fc2_w  = (const float*)d_in[13];
  const float* fc2_b  = (const float*)d_in[14];
  const float* gamma2 = (const float*)d_in[15];
  float* out = (float*)d_out;
  char* ws = (char*)d_ws;

  float*    mu1 = (float*)(ws + 0);
  float*    rs1 = (float*)(ws + 100352);
  float*    S1  = (float*)(ws + 200704);      // LN2 raw sum
  float*    S2  = (float*)(ws + 301056);      // LN2 raw sumsq
  uint8_t*  Wq  = (uint8_t*)(ws + 401408);    //   786,432 B frag-major
  uint8_t*  Wp  = (uint8_t*)(ws + 1187840);   //   262,144 B
  uint8_t*  W1  = (uint8_t*)(ws + 1449984);   // 1,048,576 B
  uint8_t*  W2  = (uint8_t*)(ws + 2498560);   // 1,048,576 B
  float*    BMt = (float*)  (ws + 3547136);   // 1,048,576 B bias+mask table
  uint8_t*  Afp = (uint8_t*)(ws + 4595712);   // 12,845,056 B frag-major tokens (LN1, later LN2)
  uint16_t* X1b = (uint16_t*)(ws + 68820992); // 25,690,112 B token-major bf16
  uint8_t*  QKV = (uint8_t*)(ws + 120201216); // 38,535,168 B token-major fp8
  uint8_t*  AT  = (uint8_t*)(ws + 158736384); // 12,845,056 B frag-major fp8
  uint8_t*  Hb  = (uint8_t*)(ws + 120201216); // 51,380,224 B frag-major, overlaps dead QKV+AT

  // zero LN2 sum buffers (atomics accumulate during proj epilogue)
  hipMemsetAsync(ws + 200704, 0, 200704, stream);

  // weights -> fp8 frag-major, BM table
  cvt_frag<512> <<<768,  256, 0, stream>>>(qkv_w, Wq, 196608);
  cvt_frag<512> <<<256,  256, 0, stream>>>(proj_w, Wp, 65536);
  cvt_frag<512> <<<1024, 256, 0, stream>>>(fc1_w, W1, 262144);
  cvt_frag<2048><<<1024, 256, 0, stream>>>(fc2_w, W2, 262144);
  bm_build<<<64, 256, 0, stream>>>(relb, BMt);

  // LN1 -> frag-major fp8 tokens
  ln_stats_nchw<<<392, 256, 0, stream>>>(x, mu1, rs1);
  ln1_apply<<<4096, 256, 0, stream>>>(x, mu1, rs1, ln1_w, ln1_b, Afp);

  // qkv GEMM (q pre-scaled): T=98, NG=24 -> grid 8*13*24 = 2496
  gemm_bl<4, 512, 0, 24, 98><<<2496, 256, 0, stream>>>(Afp, Wq, qkv_b, nullptr, nullptr, nullptr, QKV, nullptr, nullptr, nullptr, nullptr, 1536);

  // shifted-window attention (MFMA), frag-major AT out
  attn_mfma<<<2048, 256, 0, stream>>>(QKV, BMt, AT);

  // proj GEMM: X1b(bf16) = x(NCHW) + g1*(out+b); fused LN2 stats: T=98, NG=8 -> 832
  gemm_bl<4, 512, 1, 8, 98><<<832, 256, 0, stream>>>(AT, Wp, proj_b, x, nullptr, gamma1, nullptr, nullptr, X1b, S1, S2, 512);

  // LN2 apply -> frag-major fp8 tokens
  ln2_panel<<<1568, 256, 0, stream>>>(X1b, S1, S2, ln2_w, ln2_b, Afp);

  // MLP: fc1 (T=98, NG=32 -> 3328); fc2 (T=196, NG=8 -> 1600) -> NCHW out via LDS exchange
  gemm_bl<4, 512, 2, 32, 98><<<3328, 256, 0, stream>>>(Afp, W1, fc1_b, nullptr, nullptr, nullptr, Hb, nullptr, nullptr, nullptr, nullptr, 2048);
  gemm_bl<2, 2048, 3, 8, 196><<<1600, 256, 0, stream>>>(Hb, W2, fc2_b, nullptr, X1b, gamma2, nullptr, out, nullptr, nullptr, nullptr, 512);
}